// Round 6
// baseline (144.336 us; speedup 1.0000x reference)
//
#include <hip/hip_runtime.h>
#include <hip/hip_cooperative_groups.h>

namespace cg = cooperative_groups;

// Problem constants: B=8, C=3, H=W=256, mask (B,1,H,W)
#define BB 8
#define CC 3
#define HH 256
#define WW 256
#define HWC (HH * WW)

// BIG = H+W = 512. With any border present every D^2 <= 2*255^2 < BIG^2, so
// (d2 >= BIG^2) <=> image has no border pixels (reference leaves D = 0 then).
#define BIGF 512.0f
#define BIG2F 262144.0f

#define LOG2G (-0.014499569695115089f)  // log2(0.99)
#define INV_N (1.0f / 1572864.0f)       // 1/(B*C*H*W)

// Stage A geometry: 256 threads = 8 cols x 32 segments x 8 rows.
#define CT 8
#define SEGS 32
#define SR 8

#define NBLK 512  // cooperative grid

union SMem {
  struct {
    float svmax[HH][CT + 3];   // vertical max3, halo cols at 0 and CT+1
    float dend[SEGS][CT];      // local down-scan value at segment end
    float ufirst[SEGS][CT];    // first border index within segment
  } a;
  struct {
    float srow[4][WW];         // per-wave g2 row
    float swave[4];
  } b;
};

__global__ __launch_bounds__(256) void fused_kernel(
    const float* __restrict__ mask, const float* __restrict__ rec,
    const float* __restrict__ im, float* __restrict__ g2,
    float* __restrict__ partials, float* __restrict__ out) {
  __shared__ SMem sm;
  cg::grid_group grid = cg::this_grid();
  int tid = threadIdx.x;
  int bid = blockIdx.x;

  // ======== Stage A: border (3x3 maxpool - mask) + vertical EDT -> g2 ======
  if (bid < BB * (WW / CT)) {  // 256 blocks
    int cl = tid & (CT - 1);
    int seg = tid >> 3;  // 0..31
    int tile = bid & (WW / CT - 1);
    int b = bid / (WW / CT);
    int c0 = tile * CT;
    int c = c0 + cl;
    int rs = seg * SR;
    const float* mb = mask + b * HWC;

    float mcol[SR + 2];
#pragma unroll
    for (int i = 0; i < SR + 2; ++i) {
      int r = rs - 1 + i;
      r = r < 0 ? 0 : (r > HH - 1 ? HH - 1 : r);
      mcol[i] = mb[r * WW + c];
    }
#pragma unroll
    for (int i = 0; i < SR; ++i)
      sm.a.svmax[rs + i][cl + 1] = fmaxf(fmaxf(mcol[i], mcol[i + 1]), mcol[i + 2]);

    if (cl == 0 || cl == CT - 1) {  // halo columns, clamped
      int ch = (cl == 0) ? (c0 - 1 < 0 ? 0 : c0 - 1)
                         : (c0 + CT > WW - 1 ? WW - 1 : c0 + CT);
      int si = (cl == 0) ? 0 : CT + 1;
      int r0 = rs - 1 < 0 ? 0 : rs - 1;
      float h0 = mb[r0 * WW + ch];
      float h1 = mb[rs * WW + ch];
#pragma unroll
      for (int i = 0; i < SR; ++i) {
        int r2 = rs + 1 + i;
        r2 = r2 > HH - 1 ? HH - 1 : r2;
        float h2 = mb[r2 * WW + ch];
        sm.a.svmax[rs + i][si] = fmaxf(fmaxf(h0, h1), h2);
        h0 = h1;
        h1 = h2;
      }
    }
    __syncthreads();

    unsigned int bits = 0;
#pragma unroll
    for (int i = 0; i < SR; ++i) {
      float mx = fmaxf(fmaxf(sm.a.svmax[rs + i][cl], sm.a.svmax[rs + i][cl + 1]),
                       sm.a.svmax[rs + i][cl + 2]);
      if ((mx - mcol[i + 1]) > 0.5f) bits |= (1u << i);
    }

    float carry = 4096.0f;
#pragma unroll
    for (int i = 0; i < SR; ++i) carry = (bits >> i & 1u) ? 0.0f : carry + 1.0f;
    sm.a.dend[seg][cl] = carry;  // < SR iff segment contains a border
    sm.a.ufirst[seg][cl] = bits ? (float)(__ffs(bits) - 1) : 4096.0f;
    __syncthreads();

    float cinD = BIGF;
    for (int s = 0; s < seg; ++s) {
      float e = sm.a.dend[s][cl];
      cinD = (e < (float)SR) ? e : cinD + (float)SR;
    }
    float cinU = BIGF;
    for (int s = SEGS - 1; s > seg; --s) {
      float f = sm.a.ufirst[s][cl];
      cinU = (f < (float)SR) ? f : cinU + (float)SR;
    }

    float up[SR];
    float cu = 4096.0f;
#pragma unroll
    for (int i = SR - 1; i >= 0; --i) {
      cu = (bits >> i & 1u) ? 0.0f : cu + 1.0f;
      up[i] = cu;
    }
    float* gp = g2 + b * HWC + c;
    float cd = 4096.0f;
#pragma unroll
    for (int i = 0; i < SR; ++i) {
      cd = (bits >> i & 1u) ? 0.0f : cd + 1.0f;
      float d = fminf(cd, cinD + (float)(i + 1));
      float u = fminf(up[i], cinU + (float)(SR - i));
      float g = fminf(fminf(d, u), BIGF);
      gp[(rs + i) * WW] = g * g;
    }
  }

  grid.sync();  // g2 complete & visible device-wide

  // ======== Stage B: wave-per-row min-plus + weight + L1 -> partials ======
  {
    int wid = tid >> 6, lane = tid & 63;
    int row = bid * 4 + wid;  // 0..2047
    int b = row >> 8, r = row & 255;
    int base = b * HWC + r * WW;

    // Lane owns columns lane + 64*j (j=0..3): each j-quarter is a contiguous
    // 64-col region with wave-uniform activity (weight==0 where mask==0).
    float mj[4];
    bool actj[4];
    bool anyact = false;
#pragma unroll
    for (int j = 0; j < 4; ++j) {
      mj[j] = mask[base + lane + 64 * j];
      actj[j] = __ballot(mj[j] > 0.5f) != 0ULL;
      anyact |= actj[j];
    }

    float local = 0.0f;
    if (anyact)
      *(float4*)&sm.b.srow[wid][lane * 4] = *(const float4*)(g2 + base + lane * 4);
    __syncthreads();

    if (anyact) {
      float a0 = 4.0f * BIG2F, a1 = a0, a2 = a0, a3 = a0;
      float cf = (float)lane;
#pragma unroll 4
      for (int cp = 0; cp < WW; cp += 4) {
        float4 s = *(const float4*)&sm.b.srow[wid][cp];
        float d = cf - (float)cp;  // col(lane,j=0) to cp
        if (actj[0]) {
          a0 = fminf(a0, fmaf(d, d, s.x));
          float e1 = d - 1.0f, e2 = d - 2.0f, e3 = d - 3.0f;
          a0 = fminf(a0, fmaf(e1, e1, s.y));
          a0 = fminf(a0, fmaf(e2, e2, s.z));
          a0 = fminf(a0, fmaf(e3, e3, s.w));
        }
        if (actj[1]) {
          float f0 = d + 64.0f;
          a1 = fminf(a1, fmaf(f0, f0, s.x));
          float f1 = f0 - 1.0f, f2 = f0 - 2.0f, f3 = f0 - 3.0f;
          a1 = fminf(a1, fmaf(f1, f1, s.y));
          a1 = fminf(a1, fmaf(f2, f2, s.z));
          a1 = fminf(a1, fmaf(f3, f3, s.w));
        }
        if (actj[2]) {
          float f0 = d + 128.0f;
          a2 = fminf(a2, fmaf(f0, f0, s.x));
          float f1 = f0 - 1.0f, f2 = f0 - 2.0f, f3 = f0 - 3.0f;
          a2 = fminf(a2, fmaf(f1, f1, s.y));
          a2 = fminf(a2, fmaf(f2, f2, s.z));
          a2 = fminf(a2, fmaf(f3, f3, s.w));
        }
        if (actj[3]) {
          float f0 = d + 192.0f;
          a3 = fminf(a3, fmaf(f0, f0, s.x));
          float f1 = f0 - 1.0f, f2 = f0 - 2.0f, f3 = f0 - 3.0f;
          a3 = fminf(a3, fmaf(f1, f1, s.y));
          a3 = fminf(a3, fmaf(f2, f2, s.z));
          a3 = fminf(a3, fmaf(f3, f3, s.w));
        }
      }
      float aj[4] = {a0, a1, a2, a3};
#pragma unroll
      for (int j = 0; j < 4; ++j) {
        if (!actj[j]) continue;
        int c = lane + 64 * j;
        float d2v = aj[j];
        float dist = (d2v >= BIG2F) ? 0.0f : sqrtf(d2v);
        float wgt = exp2f(dist * mj[j] * LOG2G) * mj[j];
        int pbase = b * CC * HWC + r * WW + c;
        float acc = 0.0f;
#pragma unroll
        for (int ch = 0; ch < CC; ++ch)
          acc += fabsf(rec[pbase + ch * HWC] - im[pbase + ch * HWC]);
        local += wgt * acc;
      }
    }

    // unconditional wave reduce (inactive waves contribute 0)
#pragma unroll
    for (int off = 32; off > 0; off >>= 1) local += __shfl_down(local, off, 64);
    if (lane == 0) sm.b.swave[wid] = local;
    __syncthreads();
    if (tid == 0)
      partials[bid] = sm.b.swave[0] + sm.b.swave[1] + sm.b.swave[2] + sm.b.swave[3];
  }

  grid.sync();  // partials complete & visible

  // ======== Stage C: block 0 reduces 512 partials -> out[0] ========
  if (bid == 0) {
    float v = partials[tid] + partials[tid + 256];
#pragma unroll
    for (int off = 32; off > 0; off >>= 1) v += __shfl_down(v, off, 64);
    if ((tid & 63) == 0) sm.b.swave[tid >> 6] = v;
    __syncthreads();
    if (tid == 0)
      out[0] = (sm.b.swave[0] + sm.b.swave[1] + sm.b.swave[2] + sm.b.swave[3]) * INV_N;
  }
}

// ---------------------------------------------------------------------------
extern "C" void kernel_launch(void* const* d_in, const int* in_sizes, int n_in,
                              void* d_out, int out_size, void* d_ws,
                              size_t ws_size, hipStream_t stream) {
  const float* rec = (const float*)d_in[0];
  const float* im = (const float*)d_in[1];
  const float* mask = (const float*)d_in[2];
  float* out = (float*)d_out;

  float* g2 = (float*)d_ws;                           // B*H*W floats = 2 MB
  float* partials = (float*)d_ws + (size_t)BB * HWC;  // NBLK floats

  void* args[] = {(void*)&mask, (void*)&rec, (void*)&im,
                  (void*)&g2,   (void*)&partials, (void*)&out};
  hipLaunchCooperativeKernel((const void*)fused_kernel, dim3(NBLK), dim3(256),
                             args, 0, stream);
}

// Round 7
// 26.339 us; speedup vs baseline: 5.4798x; 5.4798x over previous
//
#include <hip/hip_runtime.h>

// Problem constants: B=8, C=3, H=W=256, mask (B,1,H,W)
#define BB 8
#define CC 3
#define HH 256
#define WW 256
#define HWC (HH * WW)

// BIG = H+W = 512. With any border present every D^2 <= 2*255^2 < BIG^2, so
// (d2 >= BIG^2) <=> image has no border pixels (reference leaves D = 0 then).
#define BIGF 512.0f
#define BIG2F 262144.0f

#define LOG2G (-0.014499569695115089f)  // log2(0.99)
#define INV_N (1.0f / 1572864.0f)       // 1/(B*C*H*W)

// bv geometry: 256 threads = 8 cols x 32 segments x 8 rows; 256 blocks.
#define CT 8
#define SEGS 32
#define SR 8

// ---------------------------------------------------------------------------
// Kernel 1: fused border (3x3 maxpool - mask) + vertical EDT -> g2.
// Also zeroes d_out (stream-ordered before kernel 2's atomics).
__global__ __launch_bounds__(256) void bv_kernel(
    const float* __restrict__ mask, float* __restrict__ g2,
    float* __restrict__ out) {
  __shared__ float svmax[HH][CT + 3];   // vertical max3; halo cols 0 and CT+1
  __shared__ float dend[SEGS][CT];      // local down-scan value at segment end
  __shared__ float ufirst[SEGS][CT];    // first border index within segment

  if (blockIdx.x == 0 && threadIdx.x == 0) out[0] = 0.0f;

  int tid = threadIdx.x;
  int cl = tid & (CT - 1);
  int seg = tid >> 3;  // 0..31
  int tile = blockIdx.x & (WW / CT - 1);
  int b = blockIdx.x / (WW / CT);
  int c0 = tile * CT;
  int c = c0 + cl;
  int rs = seg * SR;
  const float* mb = mask + b * HWC;

  // Own-column mask rows rs-1..rs+SR (row-clamped; duplicates harmless under
  // max -- matches 'SAME' pooling).
  float mcol[SR + 2];
#pragma unroll
  for (int i = 0; i < SR + 2; ++i) {
    int r = rs - 1 + i;
    r = r < 0 ? 0 : (r > HH - 1 ? HH - 1 : r);
    mcol[i] = mb[r * WW + c];
  }
#pragma unroll
  for (int i = 0; i < SR; ++i)
    svmax[rs + i][cl + 1] = fmaxf(fmaxf(mcol[i], mcol[i + 1]), mcol[i + 2]);

  if (cl == 0 || cl == CT - 1) {  // halo columns, clamped
    int ch = (cl == 0) ? (c0 - 1 < 0 ? 0 : c0 - 1)
                       : (c0 + CT > WW - 1 ? WW - 1 : c0 + CT);
    int si = (cl == 0) ? 0 : CT + 1;
    int r0 = rs - 1 < 0 ? 0 : rs - 1;
    float h0 = mb[r0 * WW + ch];
    float h1 = mb[rs * WW + ch];
#pragma unroll
    for (int i = 0; i < SR; ++i) {
      int r2 = rs + 1 + i;
      r2 = r2 > HH - 1 ? HH - 1 : r2;
      float h2 = mb[r2 * WW + ch];
      svmax[rs + i][si] = fmaxf(fmaxf(h0, h1), h2);
      h0 = h1;
      h1 = h2;
    }
  }
  __syncthreads();

  // Border bits: 3x3 max - mask > 0.5.
  unsigned int bits = 0;
#pragma unroll
  for (int i = 0; i < SR; ++i) {
    float mx = fmaxf(fmaxf(svmax[rs + i][cl], svmax[rs + i][cl + 1]),
                     svmax[rs + i][cl + 2]);
    if ((mx - mcol[i + 1]) > 0.5f) bits |= (1u << i);
  }

  // Segment summaries.
  float carry = 4096.0f;
#pragma unroll
  for (int i = 0; i < SR; ++i) carry = (bits >> i & 1u) ? 0.0f : carry + 1.0f;
  dend[seg][cl] = carry;  // < SR iff segment contains a border
  ufirst[seg][cl] = bits ? (float)(__ffs(bits) - 1) : 4096.0f;
  __syncthreads();

  // Carry composition across segments (image-boundary init = BIG).
  float cinD = BIGF;
  for (int s = 0; s < seg; ++s) {
    float e = dend[s][cl];
    cinD = (e < (float)SR) ? e : cinD + (float)SR;
  }
  float cinU = BIGF;
  for (int s = SEGS - 1; s > seg; --s) {
    float f = ufirst[s][cl];
    cinU = (f < (float)SR) ? f : cinU + (float)SR;
  }

  // Final corrected scans from register bits; write g^2.
  float up[SR];
  float cu = 4096.0f;
#pragma unroll
  for (int i = SR - 1; i >= 0; --i) {
    cu = (bits >> i & 1u) ? 0.0f : cu + 1.0f;
    up[i] = cu;
  }
  float* gp = g2 + b * HWC + c;
  float cd = 4096.0f;
#pragma unroll
  for (int i = 0; i < SR; ++i) {
    cd = (bits >> i & 1u) ? 0.0f : cd + 1.0f;
    float d = fminf(cd, cinD + (float)(i + 1));
    float u = fminf(up[i], cinU + (float)(SR - i));
    float g = fminf(fminf(d, u), BIGF);
    gp[(rs + i) * WW] = g * g;
  }
}

// ---------------------------------------------------------------------------
// Kernel 2: min-plus over columns (exact EDT stage 2) + weight + L1 + mean.
// 256 blocks x 256 threads; block = (b, 8-row band); wave wid owns rows
// r0+2*wid and r0+2*wid+1 with a wave-private LDS row buffer (no barriers in
// the row loop). Per-64-col-quarter ballot skip: weight==0 where mask==0, so
// dead quarters skip min-plus AND rec/im loads (exact). One atomicAdd per
// block (256 total ~ 2.6us serialized, mostly hidden under execution).
__global__ __launch_bounds__(256) void row_loss8_kernel(
    const float* __restrict__ g2, const float* __restrict__ mask,
    const float* __restrict__ rec, const float* __restrict__ im,
    float* __restrict__ out) {
  __shared__ float srow[4][WW];
  __shared__ float swave[4];
  int blk = blockIdx.x;       // 0..255
  int b = blk >> 5;           // 32 row-bands per image
  int r0 = (blk & 31) * 8;
  int wid = threadIdx.x >> 6, lane = threadIdx.x & 63;

  float local = 0.0f;
#pragma unroll
  for (int rr = 0; rr < 2; ++rr) {
    int r = r0 + wid * 2 + rr;
    int base = b * HWC + r * WW;

    float mj[4];
    bool actj[4];
    bool anyact = false;
#pragma unroll
    for (int j = 0; j < 4; ++j) {
      mj[j] = mask[base + lane + 64 * j];
      actj[j] = __ballot(mj[j] > 0.5f) != 0ULL;
      anyact |= actj[j];
    }
    if (!anyact) continue;

    // Wave-private staging of this row's g2 (no block barrier needed).
    *(float4*)&srow[wid][lane * 4] = *(const float4*)(g2 + base + lane * 4);

    float a0 = 4.0f * BIG2F, a1 = a0, a2 = a0, a3 = a0;
    float cf = (float)lane;
#pragma unroll 4
    for (int cp = 0; cp < WW; cp += 4) {
      float4 s = *(const float4*)&srow[wid][cp];
      float d = cf - (float)cp;  // col(lane, j=0) to cp
      if (actj[0]) {
        float e1 = d - 1.0f, e2 = d - 2.0f, e3 = d - 3.0f;
        a0 = fminf(a0, fmaf(d, d, s.x));
        a0 = fminf(a0, fmaf(e1, e1, s.y));
        a0 = fminf(a0, fmaf(e2, e2, s.z));
        a0 = fminf(a0, fmaf(e3, e3, s.w));
      }
      if (actj[1]) {
        float f0 = d + 64.0f, f1 = d + 63.0f, f2 = d + 62.0f, f3 = d + 61.0f;
        a1 = fminf(a1, fmaf(f0, f0, s.x));
        a1 = fminf(a1, fmaf(f1, f1, s.y));
        a1 = fminf(a1, fmaf(f2, f2, s.z));
        a1 = fminf(a1, fmaf(f3, f3, s.w));
      }
      if (actj[2]) {
        float f0 = d + 128.0f, f1 = d + 127.0f, f2 = d + 126.0f, f3 = d + 125.0f;
        a2 = fminf(a2, fmaf(f0, f0, s.x));
        a2 = fminf(a2, fmaf(f1, f1, s.y));
        a2 = fminf(a2, fmaf(f2, f2, s.z));
        a2 = fminf(a2, fmaf(f3, f3, s.w));
      }
      if (actj[3]) {
        float f0 = d + 192.0f, f1 = d + 191.0f, f2 = d + 190.0f, f3 = d + 189.0f;
        a3 = fminf(a3, fmaf(f0, f0, s.x));
        a3 = fminf(a3, fmaf(f1, f1, s.y));
        a3 = fminf(a3, fmaf(f2, f2, s.z));
        a3 = fminf(a3, fmaf(f3, f3, s.w));
      }
    }

    float aj[4] = {a0, a1, a2, a3};
#pragma unroll
    for (int j = 0; j < 4; ++j) {
      if (!actj[j]) continue;
      int c = lane + 64 * j;
      float d2v = aj[j];
      float dist = (d2v >= BIG2F) ? 0.0f : sqrtf(d2v);
      float wgt = exp2f(dist * mj[j] * LOG2G) * mj[j];
      int pbase = b * CC * HWC + r * WW + c;
      float acc = 0.0f;
#pragma unroll
      for (int ch = 0; ch < CC; ++ch)
        acc += fabsf(rec[pbase + ch * HWC] - im[pbase + ch * HWC]);
      local += wgt * acc;
    }
  }

  // Wave reduce, block reduce, one atomic per block.
#pragma unroll
  for (int off = 32; off > 0; off >>= 1) local += __shfl_down(local, off, 64);
  if (lane == 0) swave[wid] = local;
  __syncthreads();
  if (threadIdx.x == 0) {
    float s = swave[0] + swave[1] + swave[2] + swave[3];
    atomicAdd(out, s * INV_N);
  }
}

// ---------------------------------------------------------------------------
extern "C" void kernel_launch(void* const* d_in, const int* in_sizes, int n_in,
                              void* d_out, int out_size, void* d_ws,
                              size_t ws_size, hipStream_t stream) {
  const float* rec = (const float*)d_in[0];
  const float* im = (const float*)d_in[1];
  const float* mask = (const float*)d_in[2];
  float* out = (float*)d_out;

  float* g2 = (float*)d_ws;  // B*H*W floats = 2 MB

  bv_kernel<<<BB * (WW / CT), 256, 0, stream>>>(mask, g2, out);
  row_loss8_kernel<<<256, 256, 0, stream>>>(g2, mask, rec, im, out);
}